// Round 6
// baseline (128.490 us; speedup 1.0000x reference)
//
#include <hip/hip_runtime.h>
#include <hip/hip_bf16.h>

// SnakeBrain fused kernel, round 6: barrier-free, one wave per snake.
// R5 post-mortem: ~30us steady; model says DS-pipe serialization (~220
// ds_bpermute/LDS ops per wave x 16 waves/CU x 5.8cyc ~ 8.5us), 7 lock-step
// barriers/block, and ~140 L2-exposed head loads dominate. Fix: each wave
// owns a whole snake (16 MFMA m-tiles, rolling 3-tile window for stencil2),
// ZERO __syncthreads; stencil1 via direct x loads (VMEM, not DS); head via
// per-wave LDS scratch (in-order same-wave DS, lgkmcnt only) with merged
// convergent body/aux2 stage.

#define NB  4096
#define CL  256
#define HID 32
#define FIN 64

typedef __attribute__((ext_vector_type(8))) short    bf16x8;
typedef __attribute__((ext_vector_type(4))) float    f32x4;
typedef __attribute__((ext_vector_type(4))) unsigned u32x4;

__device__ __forceinline__ unsigned pkbf(float a, float b) {
    // packs bf16(a) low 16, bf16(b) high 16 (RNE, v_cvt_pk_bf16_f32)
    __hip_bfloat162 hb = __float22bfloat162_rn(make_float2(a, b));
    unsigned u; __builtin_memcpy(&u, &hb, sizeof(u));
    return u;
}
__device__ __forceinline__ float bflo(unsigned u) { return __builtin_bit_cast(float, u << 16); }
__device__ __forceinline__ float bfhi(unsigned u) { return __builtin_bit_cast(float, u & 0xffff0000u); }

// GCN chain coefficients for node n (deg incl self-loop: 3 interior, 2 ends)
__device__ __forceinline__ void gcn_coef(int n, float& nc, float& nl, float& nr) {
    const float IS3 = 0.57735026918962576f, IS2 = 0.70710678118654752f;
    const float dn = (n == 0 || n == CL - 1) ? IS2 : IS3;
    nc = dn * dn;
    nl = (n > 0)      ? dn * ((n == 1)      ? IS2 : IS3) : 0.0f;
    nr = (n < CL - 1) ? dn * ((n == CL - 2) ? IS2 : IS3) : 0.0f;
}

__global__ __launch_bounds__(256, 4) void snake_fused(
    const float* __restrict__ x,
    const float* __restrict__ heads,
    const float* __restrict__ body_sizes,
    const float* __restrict__ fruits,
    const float* __restrict__ W1, const float* __restrict__ b1,
    const float* __restrict__ W2, const float* __restrict__ b2,
    const float* __restrict__ Wr, const float* __restrict__ br,
    const float* __restrict__ Wa1, const float* __restrict__ ba1,
    const float* __restrict__ Wa2, const float* __restrict__ ba2,
    const float* __restrict__ Wc, const float* __restrict__ bc,
    const float* __restrict__ Wp, const float* __restrict__ bp,
    const float* __restrict__ Wv, const float* __restrict__ bv,
    float* __restrict__ out)
{
    // per-wave scratch, never cross-wave -> no barriers anywhere.
    // [0:32) pooled, [32:64) aux1, then reused [0:64) for cat.
    __shared__ __align__(16) float wsc[4][FIN];

    const int tid  = threadIdx.x;
    const int w    = tid >> 6;
    const int lane = tid & 63;
    const int g    = lane >> 4;     // k-group (A) / row-group (C)
    const int c    = lane & 15;     // tile col / m within tile
    const int gs   = blockIdx.x * 4 + w;   // this wave's snake

    // ---- B fragments for W2 (split bf16): B[k=8g+j][n=c+16nt] ----
    bf16x8 Bh[2], Bl[2];
    #pragma unroll
    for (int nt = 0; nt < 2; ++nt) {
        unsigned hh[4], ll[4];
        #pragma unroll
        for (int p = 0; p < 4; ++p) {
            const float wa = W2[(8 * g + 2 * p)     * HID + c + 16 * nt];
            const float wb = W2[(8 * g + 2 * p + 1) * HID + c + 16 * nt];
            const unsigned hu = pkbf(wa, wb);
            hh[p] = hu;
            ll[p] = pkbf(wa - bflo(hu), wb - bfhi(hu));
        }
        u32x4 H = {hh[0], hh[1], hh[2], hh[3]};
        u32x4 L = {ll[0], ll[1], ll[2], ll[3]};
        Bh[nt] = __builtin_bit_cast(bf16x8, H);
        Bl[nt] = __builtin_bit_cast(bf16x8, L);
    }
    const float b2v0 = b2[c], b2v1 = b2[c + 16];

    // W1/b1 slices for this lane's A-channels 8g..8g+7
    const float4 W1a0 = *(const float4*)(W1 + 8 * g);
    const float4 W1a1 = *(const float4*)(W1 + 8 * g + 4);
    const float4 W1b0 = *(const float4*)(W1 + HID + 8 * g);
    const float4 W1b1 = *(const float4*)(W1 + HID + 8 * g + 4);
    const float4 b1v0 = *(const float4*)(b1 + 8 * g);
    const float4 b1v1 = *(const float4*)(b1 + 8 * g + 4);

    const float THIRD = 0.33333333333333333f;
    const float I23   = 0.40824829046386302f;   // 1/sqrt(6)

    const float2* xs = (const float2*)x + gs * CL;

    // tile t: nodes 16t..16t+15. Lane supplies A[m=c][k=8g+j]:
    // channels 8g..8g+7 of node 16t+c. Stencil-1 done on x directly
    // (S and W1 commute); x loads are L1-hot VMEM, not DS.
    auto compute_tile = [&](int t, f32x4* accT) {
        const int m = 16 * t + c;
        const float2 xcv = xs[m];
        const float2 xlv = xs[m - (m > 0)];
        const float2 xrv = xs[m + (m < CL - 1)];
        float ncd, nld, nrd;
        if (t == 0 || t == 15) { gcn_coef(m, ncd, nld, nrd); }
        else { ncd = THIRD; nld = THIRD; nrd = THIRD; }
        const float sa = ncd * xcv.x + nld * xlv.x + nrd * xrv.x;
        const float sb = ncd * xcv.y + nld * xlv.y + nrd * xrv.y;
        const float r0 = fmaxf(fmaf(sa, W1a0.x, fmaf(sb, W1b0.x, b1v0.x)), 0.f);
        const float r1 = fmaxf(fmaf(sa, W1a0.y, fmaf(sb, W1b0.y, b1v0.y)), 0.f);
        const float r2 = fmaxf(fmaf(sa, W1a0.z, fmaf(sb, W1b0.z, b1v0.z)), 0.f);
        const float r3 = fmaxf(fmaf(sa, W1a0.w, fmaf(sb, W1b0.w, b1v0.w)), 0.f);
        const float r4 = fmaxf(fmaf(sa, W1a1.x, fmaf(sb, W1b1.x, b1v1.x)), 0.f);
        const float r5 = fmaxf(fmaf(sa, W1a1.y, fmaf(sb, W1b1.y, b1v1.y)), 0.f);
        const float r6 = fmaxf(fmaf(sa, W1a1.z, fmaf(sb, W1b1.z, b1v1.z)), 0.f);
        const float r7 = fmaxf(fmaf(sa, W1a1.w, fmaf(sb, W1b1.w, b1v1.w)), 0.f);
        const unsigned h0 = pkbf(r0, r1), h1 = pkbf(r2, r3);
        const unsigned h2 = pkbf(r4, r5), h3 = pkbf(r6, r7);
        const unsigned q0 = pkbf(r0 - bflo(h0), r1 - bfhi(h0));
        const unsigned q1 = pkbf(r2 - bflo(h1), r3 - bfhi(h1));
        const unsigned q2 = pkbf(r4 - bflo(h2), r5 - bfhi(h2));
        const unsigned q3 = pkbf(r6 - bflo(h3), r7 - bfhi(h3));
        u32x4 HU = {h0, h1, h2, h3};
        u32x4 LU = {q0, q1, q2, q3};
        const bf16x8 ah = __builtin_bit_cast(bf16x8, HU);
        const bf16x8 al = __builtin_bit_cast(bf16x8, LU);
        #pragma unroll
        for (int nt = 0; nt < 2; ++nt) {
            f32x4 a0 = {0.f, 0.f, 0.f, 0.f};
            a0 = __builtin_amdgcn_mfma_f32_16x16x32_bf16(ah, Bh[nt], a0, 0, 0, 0);
            a0 = __builtin_amdgcn_mfma_f32_16x16x32_bf16(al, Bh[nt], a0, 0, 0, 0);
            a0 = __builtin_amdgcn_mfma_f32_16x16x32_bf16(ah, Bl[nt], a0, 0, 0, 0);
            accT[nt] = a0;
        }
    };

    // ---- main loop: rolling 3-tile window, 1-deep pipeline, no barriers ----
    // C/D layout: lane holds rows 16t+4g+{0..3}, cols {c, c+16}.
    f32x4 accP[2], accC[2], accN[2];
    { f32x4 z = {0.f, 0.f, 0.f, 0.f}; accP[0] = z; accP[1] = z; accN[0] = z; accN[1] = z; }
    compute_tile(0, accC);
    float sum0 = 0.f, sum1 = 0.f;

    #pragma unroll
    for (int t = 0; t < 16; ++t) {
        if (t < 15) compute_tile(t + 1, accN);
        const bool fL = (t == 0)  && (g == 0);   // lane owns nodes 0..3
        const bool fR = (t == 15) && (g == 3);   // lane owns nodes 252..255
        const float c0  = fL ? 0.5f : THIRD;
        const float r0c = fL ? I23  : THIRD;
        const float l1c = fL ? I23  : THIRD;
        const float c3  = fR ? 0.5f : THIRD;
        const float l3c = fR ? I23  : THIRD;
        const float r2c = fR ? I23  : THIRD;
        #pragma unroll
        for (int nt = 0; nt < 2; ++nt) {
            const f32x4 v = accC[nt];
            // left neighbor of reg0 (node 16t+4g-1): sender g==3 provides prev
            // tile's reg3; receivers g==0 pull from lane c+48, else lane-16.
            const float Lsend = (g == 3) ? accP[nt][3] : v[3];
            const int   Lsrc  = (g == 0) ? (c + 48) : (lane - 16);
            float L = __shfl(Lsend, Lsrc, 64);
            if (t == 0)  L = (g == 0) ? 0.f : L;     // chain start: nl=0
            // right neighbor of reg3 (node 16t+4g+4): sender g==0 provides next
            // tile's reg0; receivers g==3 pull from lane c, else lane+16.
            const float Rsend = (g == 0) ? accN[nt][0] : v[0];
            const int   Rsrc  = (g == 3) ? c : (lane + 16);
            float R = __shfl(Rsend, Rsrc, 64);
            if (t == 15) R = (g == 3) ? 0.f : R;     // chain end: nr=0
            const float bb = nt ? b2v1 : b2v0;
            const float h0 = fmaxf(fmaf(c0,    v[0], fmaf(THIRD, L,    fmaf(r0c,   v[1], bb))), 0.f);
            const float h1 = fmaxf(fmaf(THIRD, v[1], fmaf(l1c,   v[0], fmaf(THIRD, v[2], bb))), 0.f);
            const float h2 = fmaxf(fmaf(THIRD, v[2], fmaf(THIRD, v[1], fmaf(r2c,   v[3], bb))), 0.f);
            const float h3 = fmaxf(fmaf(c3,    v[3], fmaf(l3c,   v[2], fmaf(THIRD, R,    bb))), 0.f);
            const float hs = (h0 + h1) + (h2 + h3);
            if (nt == 0) sum0 += hs; else sum1 += hs;
        }
        accP[0] = accC[0]; accP[1] = accC[1];
        accC[0] = accN[0]; accC[1] = accN[1];
    }

    // ---- mean pool: butterfly over the 4 row-groups (bits 4,5) ----
    sum0 += __shfl_xor(sum0, 16, 64); sum0 += __shfl_xor(sum0, 32, 64);
    sum1 += __shfl_xor(sum1, 16, 64); sum1 += __shfl_xor(sum1, 32, 64);
    // convergent write: 4 lanes per address write the identical value (benign)
    wsc[w][c]      = sum0 * (1.0f / CL);
    wsc[w][c + 16] = sum1 * (1.0f / CL);

    // ---- head (per wave, own snake, in-order same-wave DS -> no barrier) ----
    // aux1: lanes 32-63 (divergent if; join precedes dependent reads)
    if (lane >= 32) {
        const int cc = lane - 32;
        float a = ba1[cc];
        a = fmaf(heads[2 * gs],      Wa1[0 * HID + cc], a);
        a = fmaf(heads[2 * gs + 1],  Wa1[1 * HID + cc], a);
        a = fmaf(body_sizes[gs],     Wa1[2 * HID + cc], a);
        a = fmaf(fruits[2 * gs],     Wa1[3 * HID + cc], a);
        a = fmaf(fruits[2 * gs + 1], Wa1[4 * HID + cc], a);
        wsc[w][32 + cc] = fmaxf(a, 0.f);
    }
    // merged convergent stage: lanes 0-31 body_emb (no relu), 32-63 aux2 (relu)
    {
        const int  hh = lane >> 5;
        const int  cc = lane & 31;
        const float* Wsel = hh ? Wa2 : Wr;
        const float  bsel = hh ? ba2[cc] : br[cc];
        const float* lsel = &wsc[w][32 * hh];
        float cv = bsel;
        #pragma unroll
        for (int k4 = 0; k4 < 8; ++k4) {
            const f32x4 p = *(const f32x4*)&lsel[4 * k4];   // broadcast b128
            cv = fmaf(p[0], Wsel[(4 * k4 + 0) * HID + cc], cv);
            cv = fmaf(p[1], Wsel[(4 * k4 + 1) * HID + cc], cv);
            cv = fmaf(p[2], Wsel[(4 * k4 + 2) * HID + cc], cv);
            cv = fmaf(p[3], Wsel[(4 * k4 + 3) * HID + cc], cv);
        }
        cv = hh ? fmaxf(cv, 0.f) : cv;
        wsc[w][lane] = cv;    // cat; in-order DS: prior reads see old data
    }
    // combined = relu(cat @ Wc + bc), then logits/value butterfly
    {
        float cb = bc[lane];
        #pragma unroll
        for (int k4 = 0; k4 < 16; ++k4) {
            const f32x4 p = *(const f32x4*)&wsc[w][4 * k4];
            cb = fmaf(p[0], Wc[(4 * k4 + 0) * FIN + lane], cb);
            cb = fmaf(p[1], Wc[(4 * k4 + 1) * FIN + lane], cb);
            cb = fmaf(p[2], Wc[(4 * k4 + 2) * FIN + lane], cb);
            cb = fmaf(p[3], Wc[(4 * k4 + 3) * FIN + lane], cb);
        }
        cb = fmaxf(cb, 0.f);
        float s0 = cb * Wp[lane * 5 + 0];
        float s1 = cb * Wp[lane * 5 + 1];
        float s2 = cb * Wp[lane * 5 + 2];
        float s3 = cb * Wp[lane * 5 + 3];
        float s4 = cb * Wp[lane * 5 + 4];
        float s5 = cb * Wv[lane];
        #pragma unroll
        for (int m = 1; m <= 32; m <<= 1) {
            s0 += __shfl_xor(s0, m, 64);
            s1 += __shfl_xor(s1, m, 64);
            s2 += __shfl_xor(s2, m, 64);
            s3 += __shfl_xor(s3, m, 64);
            s4 += __shfl_xor(s4, m, 64);
            s5 += __shfl_xor(s5, m, 64);
        }
        if (lane == 0) {
            out[gs * 5 + 0] = s0 + bp[0];
            out[gs * 5 + 1] = s1 + bp[1];
            out[gs * 5 + 2] = s2 + bp[2];
            out[gs * 5 + 3] = s3 + bp[3];
            out[gs * 5 + 4] = s4 + bp[4];
            out[NB * 5 + gs] = s5 + bv[0];
        }
    }
}

extern "C" void kernel_launch(void* const* d_in, const int* in_sizes, int n_in,
                              void* d_out, int out_size, void* d_ws, size_t ws_size,
                              hipStream_t stream) {
    const float* x          = (const float*)d_in[0];
    const float* heads      = (const float*)d_in[1];
    const float* body_sizes = (const float*)d_in[2];
    const float* fruits     = (const float*)d_in[3];
    const float* W1 = (const float*)d_in[4];
    const float* b1 = (const float*)d_in[5];
    const float* W2 = (const float*)d_in[6];
    const float* b2 = (const float*)d_in[7];
    const float* Wr = (const float*)d_in[8];
    const float* br = (const float*)d_in[9];
    const float* Wa1 = (const float*)d_in[10];
    const float* ba1 = (const float*)d_in[11];
    const float* Wa2 = (const float*)d_in[12];
    const float* ba2 = (const float*)d_in[13];
    const float* Wc = (const float*)d_in[14];
    const float* bc = (const float*)d_in[15];
    const float* Wp = (const float*)d_in[16];
    const float* bp = (const float*)d_in[17];
    const float* Wv = (const float*)d_in[18];
    const float* bv = (const float*)d_in[19];

    float* out = (float*)d_out;
    snake_fused<<<NB / 4, 256, 0, stream>>>(
        x, heads, body_sizes, fruits,
        W1, b1, W2, b2, Wr, br, Wa1, ba1, Wa2, ba2,
        Wc, bc, Wp, bp, Wv, bv, out);
}